// Round 10
// baseline (683.216 us; speedup 1.0000x reference)
//
#include <hip/hip_runtime.h>
#include <stdint.h>

#define N_NODES 100000
#define N_EDGES 1600000
#define NF 128
#define NG 512
#define NC 10

#define NBUCK ((N_NODES + 255) / 256)  // 391 buckets of 256 nodes
#define EPB 8192                       // edges per block in bucket passes

#define BSTRIDE 264                    // shorts per LDS B row (256 data + 8 pad)
#define MSTRIDE 136                    // shorts per LDS mean row (128 data + 8 pad; 272B row -> 16B-aligned)

#define CVT_B 6250                     // cvt blocks
#define BT_B 384                       // build_bt blocks
#define BOUNDS_B 3                     // bounds blocks
#define COUNT_B ((N_EDGES + EPB - 1) / EPB)  // 196 bucket-count blocks

typedef short short8 __attribute__((ext_vector_type(8)));
typedef float f32x4 __attribute__((ext_vector_type(4)));

__device__ __forceinline__ unsigned short f2b(float f) {
    unsigned u = __float_as_uint(f);
    u += 0x7fffu + ((u >> 16) & 1u);
    return (unsigned short)(u >> 16);
}
__device__ __forceinline__ float lo16(unsigned v) { return __uint_as_float(v << 16); }
__device__ __forceinline__ float hi16(unsigned v) { return __uint_as_float(v & 0xffff0000u); }

// ---------------- prep: cvt (x->bf16) + build_bt + bounds + bucket_count, merged ----------------
__global__ __launch_bounds__(256) void prep_kernel(const float* __restrict__ x, unsigned short* __restrict__ xb,
                                                   const float* __restrict__ w1l, const float* __restrict__ w1r,
                                                   const float* __restrict__ w2l, const float* __restrict__ w2r,
                                                   const float* __restrict__ w3l, const float* __restrict__ w3r,
                                                   unsigned short* __restrict__ Bt,
                                                   const int* __restrict__ batch, int* __restrict__ gstart,
                                                   const int* __restrict__ dst, int* __restrict__ bcount) {
    const int b = blockIdx.x, t = threadIdx.x;
    if (b < CVT_B) {
        int i = b * 256 + t;
        const float4* ip = (const float4*)x;
        float4 a = ip[2 * i], c = ip[2 * i + 1];
        uint4 o;
        o.x = (unsigned)f2b(a.x) | ((unsigned)f2b(a.y) << 16);
        o.y = (unsigned)f2b(a.z) | ((unsigned)f2b(a.w) << 16);
        o.z = (unsigned)f2b(c.x) | ((unsigned)f2b(c.y) << 16);
        o.w = (unsigned)f2b(c.z) | ((unsigned)f2b(c.w) << 16);
        ((uint4*)xb)[i] = o;
    } else if (b < CVT_B + BT_B) {
        int i = (b - CVT_B) * 256 + t;
        int layer = i / (128 * 256);
        int r = i % (128 * 256);
        int n = r / 256, k = r % 256;
        const float* wl = (layer == 0) ? w1l : (layer == 1) ? w2l : w3l;
        const float* wr = (layer == 0) ? w1r : (layer == 1) ? w2r : w3r;
        float v = (k < 128) ? wl[k * 128 + n] : wr[(k - 128) * 128 + n];
        Bt[i] = f2b(v);
    } else if (b < CVT_B + BT_B + BOUNDS_B) {
        int g = (b - CVT_B - BT_B) * 256 + t;
        if (g > NG) return;
        int lo = 0, hi = N_NODES;
        while (lo < hi) {
            int mid = (lo + hi) >> 1;
            if (batch[mid] < g) lo = mid + 1; else hi = mid;
        }
        gstart[g] = lo;
    } else {
        __shared__ int h[NBUCK];
        for (int i = t; i < NBUCK; i += 256) h[i] = 0;
        __syncthreads();
        const int base = (b - CVT_B - BT_B - BOUNDS_B) * EPB;
        const int lim = min(base + EPB, N_EDGES);
        for (int i = base + t; i < lim; i += 256) atomicAdd(&h[dst[i] >> 8], 1);
        __syncthreads();
        for (int i = t; i < NBUCK; i += 256)
            if (h[i]) atomicAdd(&bcount[i], h[i]);
    }
}

// ---------------- CSR build (scan / scatter / fill) ----------------
__global__ __launch_bounds__(512) void bucket_scan(const int* __restrict__ bcount, int* __restrict__ bbase,
                                                   int* __restrict__ gcursor, int* __restrict__ rowptr) {
    __shared__ int sh[512];
    const int t = threadIdx.x;
    int v = (t < NBUCK) ? bcount[t] : 0;
    sh[t] = v;
    __syncthreads();
    for (int off = 1; off < 512; off <<= 1) {
        int u = (t >= off) ? sh[t - off] : 0;
        __syncthreads();
        sh[t] += u;
        __syncthreads();
    }
    if (t < NBUCK) {
        int e = sh[t] - v;
        bbase[t] = e;
        gcursor[t] = e;
    }
    if (t == NBUCK - 1) bbase[NBUCK] = sh[t];
    if (t == 0) rowptr[N_NODES] = N_EDGES;
}

__global__ __launch_bounds__(256) void bucket_scatter(const int* __restrict__ src, const int* __restrict__ dst,
                                                      int* __restrict__ gcursor, unsigned* __restrict__ brec) {
    __shared__ int h[NBUCK];
    for (int i = threadIdx.x; i < NBUCK; i += 256) h[i] = 0;
    __syncthreads();
    const int base = blockIdx.x * EPB;
    const int lim = min(base + EPB, N_EDGES);
    for (int i = base + threadIdx.x; i < lim; i += 256) atomicAdd(&h[dst[i] >> 8], 1);
    __syncthreads();
    for (int i = threadIdx.x; i < NBUCK; i += 256) {
        int c = h[i];
        if (c) h[i] = atomicAdd(&gcursor[i], c);
    }
    __syncthreads();
    for (int i = base + threadIdx.x; i < lim; i += 256) {
        int d = dst[i];
        int pos = atomicAdd(&h[d >> 8], 1);
        brec[pos] = ((unsigned)(d & 255) << 17) | (unsigned)src[i];
    }
}

__global__ __launch_bounds__(256) void bucket_fill(const unsigned* __restrict__ brec, const int* __restrict__ bbase,
                                                   int* __restrict__ rowptr, int* __restrict__ eidx) {
    __shared__ int nh[256];
    __shared__ int sc[256];
    const int b = blockIdx.x, t = threadIdx.x;
    const int beg = bbase[b], end = bbase[b + 1];
    nh[t] = 0;
    __syncthreads();
    for (int i = beg + t; i < end; i += 256) atomicAdd(&nh[brec[i] >> 17], 1);
    __syncthreads();
    int cnt = nh[t];
    sc[t] = cnt;
    __syncthreads();
    for (int off = 1; off < 256; off <<= 1) {
        int u = (t >= off) ? sc[t - off] : 0;
        __syncthreads();
        sc[t] += u;
        __syncthreads();
    }
    int excl = sc[t] - cnt;
    int node = b * 256 + t;
    if (node < N_NODES) rowptr[node] = beg + excl;
    nh[t] = beg + excl;
    __syncthreads();
    for (int i = beg + t; i < end; i += 256) {
        unsigned r = brec[i];
        int pos = atomicAdd(&nh[r >> 17], 1);
        eidx[pos] = (int)(r & 0x1FFFFu);
    }
}

// ---------------- fused SAGE layer: gather-mean (LDS) + GEMM + relu (+ optional gate) ----------------
// Block = 64 dst rows. Phase 1: each wave gathers/means 16 nodes into LDS.
// Phase 2: two col-passes; each stages 64 Bt rows into a shared LDS buffer, then
// each wave does its 16-row tile x 64 cols with 16x16x32 MFMA. Identity-A frags
// (k>=128, from F) cached in registers across passes so F is read once.
__global__ __launch_bounds__(256) void fused_layer(const unsigned short* __restrict__ F,
                                                   const int* __restrict__ rowptr,
                                                   const int* __restrict__ eidx,
                                                   const unsigned short* __restrict__ Bt,
                                                   const float* __restrict__ bias,
                                                   unsigned short* __restrict__ Out,
                                                   const float* __restrict__ gatew,
                                                   const float* __restrict__ gateb,
                                                   float* __restrict__ gate) {
    const int t = threadIdx.x;
    const int wave = t >> 6, lane = t & 63;
    const int lrow = lane & 15, quad = lane >> 4;
    const int row0 = blockIdx.x * 64;

    __shared__ __attribute__((aligned(16))) unsigned short meanS[64 * MSTRIDE];  // 17.4 KB
    __shared__ __attribute__((aligned(16))) unsigned short Bs[64 * BSTRIDE];     // 33.8 KB

    const uint4* F4 = (const uint4*)F;

    // ---- phase 1: gather means for this block's 64 rows (wave w -> nodes w*16..w*16+15) ----
    for (int n = 0; n < 16; ++n) {
        int node = row0 + wave * 16 + n;
        if (node >= N_NODES) break;  // wave-uniform
        const int beg = rowptr[node], end = rowptr[node + 1];
        float a0 = 0.f, a1 = 0.f, a2 = 0.f, a3 = 0.f, a4 = 0.f, a5 = 0.f, a6 = 0.f, a7 = 0.f;
        int e = beg + quad;
        for (; e + 12 < end; e += 16) {
            int r0 = eidx[e];
            int r1 = eidx[e + 4];
            int r2 = eidx[e + 8];
            int r3 = eidx[e + 12];
            uint4 v0 = F4[(size_t)r0 * 16 + lrow];
            uint4 v1 = F4[(size_t)r1 * 16 + lrow];
            uint4 v2 = F4[(size_t)r2 * 16 + lrow];
            uint4 v3 = F4[(size_t)r3 * 16 + lrow];
            a0 += lo16(v0.x) + lo16(v1.x) + lo16(v2.x) + lo16(v3.x);
            a1 += hi16(v0.x) + hi16(v1.x) + hi16(v2.x) + hi16(v3.x);
            a2 += lo16(v0.y) + lo16(v1.y) + lo16(v2.y) + lo16(v3.y);
            a3 += hi16(v0.y) + hi16(v1.y) + hi16(v2.y) + hi16(v3.y);
            a4 += lo16(v0.z) + lo16(v1.z) + lo16(v2.z) + lo16(v3.z);
            a5 += hi16(v0.z) + hi16(v1.z) + hi16(v2.z) + hi16(v3.z);
            a6 += lo16(v0.w) + lo16(v1.w) + lo16(v2.w) + lo16(v3.w);
            a7 += hi16(v0.w) + hi16(v1.w) + hi16(v2.w) + hi16(v3.w);
        }
        for (; e < end; e += 4) {
            uint4 v0 = F4[(size_t)eidx[e] * 16 + lrow];
            a0 += lo16(v0.x); a1 += hi16(v0.x);
            a2 += lo16(v0.y); a3 += hi16(v0.y);
            a4 += lo16(v0.z); a5 += hi16(v0.z);
            a6 += lo16(v0.w); a7 += hi16(v0.w);
        }
        a0 += __shfl_xor(a0, 16); a0 += __shfl_xor(a0, 32);
        a1 += __shfl_xor(a1, 16); a1 += __shfl_xor(a1, 32);
        a2 += __shfl_xor(a2, 16); a2 += __shfl_xor(a2, 32);
        a3 += __shfl_xor(a3, 16); a3 += __shfl_xor(a3, 32);
        a4 += __shfl_xor(a4, 16); a4 += __shfl_xor(a4, 32);
        a5 += __shfl_xor(a5, 16); a5 += __shfl_xor(a5, 32);
        a6 += __shfl_xor(a6, 16); a6 += __shfl_xor(a6, 32);
        a7 += __shfl_xor(a7, 16); a7 += __shfl_xor(a7, 32);
        if (quad == 0) {
            float inv = 1.0f / (float)max(end - beg, 1);
            uint4 o;
            o.x = (unsigned)f2b(a0 * inv) | ((unsigned)f2b(a1 * inv) << 16);
            o.y = (unsigned)f2b(a2 * inv) | ((unsigned)f2b(a3 * inv) << 16);
            o.z = (unsigned)f2b(a4 * inv) | ((unsigned)f2b(a5 * inv) << 16);
            o.w = (unsigned)f2b(a6 * inv) | ((unsigned)f2b(a7 * inv) << 16);
            *(uint4*)(meanS + (wave * 16 + n) * MSTRIDE + lrow * 8) = o;
        }
    }
    __syncthreads();

    // ---- phase 2: two col-passes over shared Bs buffer ----
    int arow = row0 + wave * 16 + lrow;
    if (arow > N_NODES - 1) arow = N_NODES - 1;

    float gpart[4] = {0.f, 0.f, 0.f, 0.f};
    short8 afg[4];  // cached identity-A fragments (k = 128..255), loaded in pass 0

    for (int pass = 0; pass < 2; ++pass) {
        if (pass) __syncthreads();  // all waves done reading Bs pass 0
        // stage Bt rows [pass*64, pass*64+64): 64 rows x 32 uint4 = 2048 units, 8/thread
#pragma unroll
        for (int i = 0; i < 8; ++i) {
            int u = t + i * 256;
            int r = u >> 5, seg = u & 31;
            *(uint4*)(Bs + r * BSTRIDE + seg * 8) =
                *(const uint4*)(Bt + (size_t)(pass * 64 + r) * 256 + seg * 8);
        }
        __syncthreads();

        f32x4 acc[4];
#pragma unroll
        for (int j = 0; j < 4; ++j) acc[j] = (f32x4){0.f, 0.f, 0.f, 0.f};

#pragma unroll
        for (int c = 0; c < 8; ++c) {
            short8 af;
            if (c < 4) {
                af = *(const short8*)(meanS + (wave * 16 + lrow) * MSTRIDE + c * 32 + quad * 8);
            } else {
                if (pass == 0)
                    afg[c - 4] = *(const short8*)(F + (size_t)arow * 128 + (c - 4) * 32 + quad * 8);
                af = afg[c - 4];
            }
            const int kf = c * 32 + quad * 8;
#pragma unroll
            for (int j = 0; j < 4; ++j) {
                short8 bf = *(const short8*)(Bs + (j * 16 + lrow) * BSTRIDE + kf);
                acc[j] = __builtin_amdgcn_mfma_f32_16x16x32_bf16(af, bf, acc[j], 0, 0, 0);
            }
        }

#pragma unroll
        for (int j = 0; j < 4; ++j) {
            int col = pass * 64 + j * 16 + lrow;
            float bc = bias[col];
            float gw = gatew ? gatew[col] : 0.f;
#pragma unroll
            for (int r = 0; r < 4; ++r) {
                int row = row0 + wave * 16 + quad * 4 + r;
                if (row < N_NODES) {
                    float v = fmaxf(acc[j][r] + bc, 0.f);
                    Out[(size_t)row * 128 + col] = f2b(v);
                    gpart[r] += v * gw;
                }
            }
        }
    }

    if (gatew) {
        float gb = gateb[0];
#pragma unroll
        for (int r = 0; r < 4; ++r) {
            float g = gpart[r];
            g += __shfl_xor(g, 1);
            g += __shfl_xor(g, 2);
            g += __shfl_xor(g, 4);
            g += __shfl_xor(g, 8);
            if (lrow == 0) {
                int row = row0 + wave * 16 + quad * 4 + r;
                if (row < N_NODES) gate[row] = g + gb;
            }
        }
    }
}

// ---------------- fused attention-pool + MLP + log_softmax ----------------
__global__ __launch_bounds__(256) void pool_mlp_kernel(const unsigned short* __restrict__ h,
                                                       const float* __restrict__ gate,
                                                       const int* __restrict__ gstart,
                                                       const float* __restrict__ l1w,
                                                       const float* __restrict__ l1b,
                                                       const float* __restrict__ l2w,
                                                       const float* __restrict__ l2b,
                                                       float* __restrict__ out) {
    int wv = threadIdx.x >> 6;
    int g = blockIdx.x * 4 + wv;
    int lane = threadIdx.x & 63;
    __shared__ float pooled_s[4][128];
    __shared__ float hid_s[4][128];
    if (g >= NG) return;

    int beg = gstart[g], end = gstart[g + 1];

    float m = -INFINITY;
    for (int i = beg + lane; i < end; i += 64) m = fmaxf(m, gate[i]);
#pragma unroll
    for (int o = 32; o; o >>= 1) m = fmaxf(m, __shfl_xor(m, o));
    float s = 0.f;
    for (int i = beg + lane; i < end; i += 64) s += expf(gate[i] - m);
#pragma unroll
    for (int o = 32; o; o >>= 1) s += __shfl_xor(s, o);
    float invs = (s > 0.f) ? 1.0f / s : 0.f;

    float ax = 0.f, ay = 0.f;
    const unsigned* hb = (const unsigned*)h;
    int i = beg;
    for (; i + 2 <= end; i += 2) {
        float w0 = expf(gate[i] - m) * invs;
        float w1 = expf(gate[i + 1] - m) * invs;
        unsigned v0 = hb[(size_t)i * 64 + lane];
        unsigned v1 = hb[(size_t)(i + 1) * 64 + lane];
        ax += w0 * lo16(v0) + w1 * lo16(v1);
        ay += w0 * hi16(v0) + w1 * hi16(v1);
    }
    for (; i < end; ++i) {
        float w = expf(gate[i] - m) * invs;
        unsigned v = hb[(size_t)i * 64 + lane];
        ax += w * lo16(v);
        ay += w * hi16(v);
    }
    pooled_s[wv][2 * lane] = ax;
    pooled_s[wv][2 * lane + 1] = ay;

    float h0 = l1b[lane], h1 = l1b[lane + 64];
    for (int k = 0; k < 128; ++k) {
        float pv = pooled_s[wv][k];
        h0 += pv * l1w[k * 128 + lane];
        h1 += pv * l1w[k * 128 + lane + 64];
    }
    hid_s[wv][lane] = fmaxf(h0, 0.f);
    hid_s[wv][lane + 64] = fmaxf(h1, 0.f);

    float o10 = 0.f;
    if (lane < NC) {
        o10 = l2b[lane];
        for (int k = 0; k < 128; ++k) o10 += hid_s[wv][k] * l2w[k * NC + lane];
    }
    float mm = -INFINITY;
#pragma unroll
    for (int j = 0; j < NC; ++j) mm = fmaxf(mm, __shfl(o10, j));
    float ss = 0.f;
#pragma unroll
    for (int j = 0; j < NC; ++j) ss += expf(__shfl(o10, j) - mm);
    float lse = mm + logf(ss);
    if (lane < NC) out[g * NC + lane] = o10 - lse;
}

extern "C" void kernel_launch(void* const* d_in, const int* in_sizes, int n_in,
                              void* d_out, int out_size, void* d_ws, size_t ws_size,
                              hipStream_t stream) {
    const float* x   = (const float*)d_in[0];
    const int* ei    = (const int*)d_in[1];
    const int* batch = (const int*)d_in[2];
    const float* w1l = (const float*)d_in[3];
    const float* b1  = (const float*)d_in[4];
    const float* w1r = (const float*)d_in[5];
    const float* w2l = (const float*)d_in[6];
    const float* b2  = (const float*)d_in[7];
    const float* w2r = (const float*)d_in[8];
    const float* w3l = (const float*)d_in[9];
    const float* b3  = (const float*)d_in[10];
    const float* w3r = (const float*)d_in[11];
    const float* gw  = (const float*)d_in[12];
    const float* gb  = (const float*)d_in[13];
    const float* l1w = (const float*)d_in[14];
    const float* l1b = (const float*)d_in[15];
    const float* l2w = (const float*)d_in[16];
    const float* l2b = (const float*)d_in[17];
    float* out = (float*)d_out;

    const int* src = ei;
    const int* dst = ei + N_EDGES;

    char* base = (char*)d_ws;
    size_t off = 0;
    auto carve = [&](size_t bytes) -> void* {
        void* r = base + off;
        off = (off + bytes + 255) & ~(size_t)255;
        return r;
    };
    int* rowptr         = (int*)carve((size_t)(N_NODES + 1) * 4);
    int* eidx           = (int*)carve((size_t)N_EDGES * 4);
    unsigned short* Bt  = (unsigned short*)carve((size_t)3 * 128 * 256 * 2);
    unsigned short* xb  = (unsigned short*)carve((size_t)N_NODES * NF * 2);
    unsigned short* hA  = (unsigned short*)carve((size_t)N_NODES * NF * 2);
    unsigned short* hB  = (unsigned short*)carve((size_t)N_NODES * NF * 2);
    float* gate         = (float*)carve((size_t)N_NODES * 4);
    int* gstart         = (int*)carve(513 * 4);
    int* bcount         = (int*)carve((NBUCK + 1) * 4);
    int* bbase          = (int*)carve((NBUCK + 1) * 4);
    int* gcursor        = (int*)carve((NBUCK + 1) * 4);
    unsigned* brec      = (unsigned*)hB;  // alias: hB is dead until layer 2's output

    hipMemsetAsync(bcount, 0, (size_t)NBUCK * 4, stream);

    prep_kernel<<<CVT_B + BT_B + BOUNDS_B + COUNT_B, 256, 0, stream>>>(
        x, xb, w1l, w1r, w2l, w2r, w3l, w3r, Bt, batch, gstart, dst, bcount);

    bucket_scan<<<1, 512, 0, stream>>>(bcount, bbase, gcursor, rowptr);
    bucket_scatter<<<COUNT_B, 256, 0, stream>>>(src, dst, gcursor, brec);
    bucket_fill<<<NBUCK, 256, 0, stream>>>(brec, bbase, rowptr, eidx);

    const int FL_B = (N_NODES + 63) / 64;  // 1563

    fused_layer<<<FL_B, 256, 0, stream>>>(xb, rowptr, eidx, Bt, b1, hA, nullptr, nullptr, nullptr);
    fused_layer<<<FL_B, 256, 0, stream>>>(hA, rowptr, eidx, Bt + 32768, b2, hB, nullptr, nullptr, nullptr);
    fused_layer<<<FL_B, 256, 0, stream>>>(hB, rowptr, eidx, Bt + 65536, b3, hA, gw, gb, gate);

    pool_mlp_kernel<<<(NG + 3) / 4, 256, 0, stream>>>(hA, gate, gstart, l1w, l1b, l2w, l2b, out);
}

// Round 11
// 581.508 us; speedup vs baseline: 1.1749x; 1.1749x over previous
//
#include <hip/hip_runtime.h>
#include <stdint.h>

#define N_NODES 100000
#define N_EDGES 1600000
#define NF 128
#define NG 512
#define NC 10

#define NBUCK ((N_NODES + 255) / 256)  // 391 buckets of 256 nodes
#define EPB 4096                       // edges per block in bucket passes

#define BSTRIDE 264                    // shorts per LDS B row (256 data + 8 pad)
#define GEMM_GRID 512                  // 2 blocks/CU; grid-stride over 64-row tiles
#define N_TILES ((N_NODES + 63) / 64)  // 1563

#define CVT_B 6250                     // cvt blocks
#define BT_B 384                       // build_bt blocks
#define BOUNDS_B 3                     // bounds blocks
#define COUNT_B ((N_EDGES + EPB - 1) / EPB)  // 391 bucket-count blocks

typedef short short8 __attribute__((ext_vector_type(8)));
typedef float f32x4 __attribute__((ext_vector_type(4)));

__device__ __forceinline__ unsigned short f2b(float f) {
    unsigned u = __float_as_uint(f);
    u += 0x7fffu + ((u >> 16) & 1u);
    return (unsigned short)(u >> 16);
}
__device__ __forceinline__ float lo16(unsigned v) { return __uint_as_float(v << 16); }
__device__ __forceinline__ float hi16(unsigned v) { return __uint_as_float(v & 0xffff0000u); }

// ---------------- prep: cvt (x->bf16) + build_bt + bounds + bucket_count, merged ----------------
__global__ __launch_bounds__(256) void prep_kernel(const float* __restrict__ x, unsigned short* __restrict__ xb,
                                                   const float* __restrict__ w1l, const float* __restrict__ w1r,
                                                   const float* __restrict__ w2l, const float* __restrict__ w2r,
                                                   const float* __restrict__ w3l, const float* __restrict__ w3r,
                                                   unsigned short* __restrict__ Bt,
                                                   const int* __restrict__ batch, int* __restrict__ gstart,
                                                   const int* __restrict__ dst, int* __restrict__ bcount) {
    const int b = blockIdx.x, t = threadIdx.x;
    if (b < CVT_B) {
        int i = b * 256 + t;
        const float4* ip = (const float4*)x;
        float4 a = ip[2 * i], c = ip[2 * i + 1];
        uint4 o;
        o.x = (unsigned)f2b(a.x) | ((unsigned)f2b(a.y) << 16);
        o.y = (unsigned)f2b(a.z) | ((unsigned)f2b(a.w) << 16);
        o.z = (unsigned)f2b(c.x) | ((unsigned)f2b(c.y) << 16);
        o.w = (unsigned)f2b(c.z) | ((unsigned)f2b(c.w) << 16);
        ((uint4*)xb)[i] = o;
    } else if (b < CVT_B + BT_B) {
        int i = (b - CVT_B) * 256 + t;
        int layer = i / (128 * 256);
        int r = i % (128 * 256);
        int n = r / 256, k = r % 256;
        const float* wl = (layer == 0) ? w1l : (layer == 1) ? w2l : w3l;
        const float* wr = (layer == 0) ? w1r : (layer == 1) ? w2r : w3r;
        float v = (k < 128) ? wl[k * 128 + n] : wr[(k - 128) * 128 + n];
        Bt[i] = f2b(v);
    } else if (b < CVT_B + BT_B + BOUNDS_B) {
        int g = (b - CVT_B - BT_B) * 256 + t;
        if (g > NG) return;
        int lo = 0, hi = N_NODES;
        while (lo < hi) {
            int mid = (lo + hi) >> 1;
            if (batch[mid] < g) lo = mid + 1; else hi = mid;
        }
        gstart[g] = lo;
    } else {
        __shared__ int h[NBUCK];
        for (int i = t; i < NBUCK; i += 256) h[i] = 0;
        __syncthreads();
        const int base = (b - CVT_B - BT_B - BOUNDS_B) * EPB;
        const int lim = min(base + EPB, N_EDGES);
        for (int i = base + t; i < lim; i += 256) atomicAdd(&h[dst[i] >> 8], 1);
        __syncthreads();
        for (int i = t; i < NBUCK; i += 256)
            if (h[i]) atomicAdd(&bcount[i], h[i]);
    }
}

// ---------------- CSR build (scan / scatter / fill) ----------------
__global__ __launch_bounds__(512) void bucket_scan(const int* __restrict__ bcount, int* __restrict__ bbase,
                                                   int* __restrict__ gcursor, int* __restrict__ rowptr) {
    __shared__ int sh[512];
    const int t = threadIdx.x;
    int v = (t < NBUCK) ? bcount[t] : 0;
    sh[t] = v;
    __syncthreads();
    for (int off = 1; off < 512; off <<= 1) {
        int u = (t >= off) ? sh[t - off] : 0;
        __syncthreads();
        sh[t] += u;
        __syncthreads();
    }
    if (t < NBUCK) {
        int e = sh[t] - v;
        bbase[t] = e;
        gcursor[t] = e;
    }
    if (t == NBUCK - 1) bbase[NBUCK] = sh[t];
    if (t == 0) rowptr[N_NODES] = N_EDGES;
}

__global__ __launch_bounds__(256) void bucket_scatter(const int* __restrict__ src, const int* __restrict__ dst,
                                                      int* __restrict__ gcursor, unsigned* __restrict__ brec) {
    __shared__ int h[NBUCK];
    for (int i = threadIdx.x; i < NBUCK; i += 256) h[i] = 0;
    __syncthreads();
    const int base = blockIdx.x * EPB;
    const int lim = min(base + EPB, N_EDGES);
    for (int i = base + threadIdx.x; i < lim; i += 256) atomicAdd(&h[dst[i] >> 8], 1);
    __syncthreads();
    for (int i = threadIdx.x; i < NBUCK; i += 256) {
        int c = h[i];
        if (c) h[i] = atomicAdd(&gcursor[i], c);
    }
    __syncthreads();
    for (int i = base + threadIdx.x; i < lim; i += 256) {
        int d = dst[i];
        int pos = atomicAdd(&h[d >> 8], 1);
        brec[pos] = ((unsigned)(d & 255) << 17) | (unsigned)src[i];
    }
}

__global__ __launch_bounds__(256) void bucket_fill(const unsigned* __restrict__ brec, const int* __restrict__ bbase,
                                                   int* __restrict__ rowptr, int* __restrict__ eidx) {
    __shared__ int nh[256];
    __shared__ int sc[256];
    const int b = blockIdx.x, t = threadIdx.x;
    const int beg = bbase[b], end = bbase[b + 1];
    nh[t] = 0;
    __syncthreads();
    for (int i = beg + t; i < end; i += 256) atomicAdd(&nh[brec[i] >> 17], 1);
    __syncthreads();
    int cnt = nh[t];
    sc[t] = cnt;
    __syncthreads();
    for (int off = 1; off < 256; off <<= 1) {
        int u = (t >= off) ? sc[t - off] : 0;
        __syncthreads();
        sc[t] += u;
        __syncthreads();
    }
    int excl = sc[t] - cnt;
    int node = b * 256 + t;
    if (node < N_NODES) rowptr[node] = beg + excl;
    nh[t] = beg + excl;
    __syncthreads();
    for (int i = beg + t; i < end; i += 256) {
        unsigned r = brec[i];
        int pos = atomicAdd(&nh[r >> 17], 1);
        eidx[pos] = (int)(r & 0x1FFFFu);
    }
}

// ---------------- mean aggregation: one wave per node; quad q owns edges beg+q, beg+q+4, ... ----------------
__global__ __launch_bounds__(256) void agg_kernel(const unsigned short* __restrict__ F,
                                                  const int* __restrict__ rowptr,
                                                  const int* __restrict__ eidx,
                                                  unsigned short* __restrict__ M) {
    int node = blockIdx.x * 4 + (threadIdx.x >> 6);
    if (node >= N_NODES) return;
    const int lane = threadIdx.x & 63;
    const int quad = lane >> 4, ql = lane & 15;
    const int beg = rowptr[node], end = rowptr[node + 1];
    const uint4* F4 = (const uint4*)F;

    float a0 = 0.f, a1 = 0.f, a2 = 0.f, a3 = 0.f, a4 = 0.f, a5 = 0.f, a6 = 0.f, a7 = 0.f;
    int t = beg + quad;
    for (; t + 12 < end; t += 16) {
        int r0 = eidx[t];
        int r1 = eidx[t + 4];
        int r2 = eidx[t + 8];
        int r3 = eidx[t + 12];
        uint4 v0 = F4[(size_t)r0 * 16 + ql];
        uint4 v1 = F4[(size_t)r1 * 16 + ql];
        uint4 v2 = F4[(size_t)r2 * 16 + ql];
        uint4 v3 = F4[(size_t)r3 * 16 + ql];
        a0 += lo16(v0.x) + lo16(v1.x) + lo16(v2.x) + lo16(v3.x);
        a1 += hi16(v0.x) + hi16(v1.x) + hi16(v2.x) + hi16(v3.x);
        a2 += lo16(v0.y) + lo16(v1.y) + lo16(v2.y) + lo16(v3.y);
        a3 += hi16(v0.y) + hi16(v1.y) + hi16(v2.y) + hi16(v3.y);
        a4 += lo16(v0.z) + lo16(v1.z) + lo16(v2.z) + lo16(v3.z);
        a5 += hi16(v0.z) + hi16(v1.z) + hi16(v2.z) + hi16(v3.z);
        a6 += lo16(v0.w) + lo16(v1.w) + lo16(v2.w) + lo16(v3.w);
        a7 += hi16(v0.w) + hi16(v1.w) + hi16(v2.w) + hi16(v3.w);
    }
    for (; t < end; t += 4) {
        uint4 v0 = F4[(size_t)eidx[t] * 16 + ql];
        a0 += lo16(v0.x); a1 += hi16(v0.x);
        a2 += lo16(v0.y); a3 += hi16(v0.y);
        a4 += lo16(v0.z); a5 += hi16(v0.z);
        a6 += lo16(v0.w); a7 += hi16(v0.w);
    }
    a0 += __shfl_xor(a0, 16); a0 += __shfl_xor(a0, 32);
    a1 += __shfl_xor(a1, 16); a1 += __shfl_xor(a1, 32);
    a2 += __shfl_xor(a2, 16); a2 += __shfl_xor(a2, 32);
    a3 += __shfl_xor(a3, 16); a3 += __shfl_xor(a3, 32);
    a4 += __shfl_xor(a4, 16); a4 += __shfl_xor(a4, 32);
    a5 += __shfl_xor(a5, 16); a5 += __shfl_xor(a5, 32);
    a6 += __shfl_xor(a6, 16); a6 += __shfl_xor(a6, 32);
    a7 += __shfl_xor(a7, 16); a7 += __shfl_xor(a7, 32);

    if (quad == 0) {
        float inv = 1.0f / (float)max(end - beg, 1);
        uint4 o;
        o.x = (unsigned)f2b(a0 * inv) | ((unsigned)f2b(a1 * inv) << 16);
        o.y = (unsigned)f2b(a2 * inv) | ((unsigned)f2b(a3 * inv) << 16);
        o.z = (unsigned)f2b(a4 * inv) | ((unsigned)f2b(a5 * inv) << 16);
        o.w = (unsigned)f2b(a6 * inv) | ((unsigned)f2b(a7 * inv) << 16);
        ((uint4*)M)[(size_t)node * 16 + ql] = o;
    }
}

// ---------------- GEMM: H = relu([mean|feat] @ Bt^T + b), optional fused gate ----------------
// B (128x256, 64KB) staged to LDS once per block; grid-stride over 64-row tiles;
// each wave computes 16 rows x 128 cols with 16x16x32 MFMA.
__global__ __launch_bounds__(256, 2) void gemm_kernel(const unsigned short* __restrict__ Am,
                                                      const unsigned short* __restrict__ Ax,
                                                      const unsigned short* __restrict__ Bt,
                                                      const float* __restrict__ bias,
                                                      unsigned short* __restrict__ Out,
                                                      const float* __restrict__ gatew,
                                                      const float* __restrict__ gateb,
                                                      float* __restrict__ gate) {
    const int t = threadIdx.x;
    const int wave = t >> 6, lane = t & 63;
    const int lrow = lane & 15, quad = lane >> 4;

    __shared__ __attribute__((aligned(16))) unsigned short Bs[128 * BSTRIDE];

#pragma unroll
    for (int i = 0; i < 16; ++i) {
        int u = t + i * 256;
        int r = u >> 5, seg = u & 31;
        *(uint4*)(Bs + r * BSTRIDE + seg * 8) = *(const uint4*)(Bt + r * 256 + seg * 8);
    }
    __syncthreads();

    for (int tile = blockIdx.x; tile < N_TILES; tile += GEMM_GRID) {
        const int row0 = tile * 64 + wave * 16;
        int arow = row0 + lrow;
        if (arow > N_NODES - 1) arow = N_NODES - 1;

        f32x4 acc[8];
#pragma unroll
        for (int nt = 0; nt < 8; ++nt) acc[nt] = (f32x4){0.f, 0.f, 0.f, 0.f};

#pragma unroll
        for (int c = 0; c < 8; ++c) {
            const unsigned short* Aarr = (c < 4) ? Am : Ax;
            const int kb = (c & 3) * 32 + quad * 8;
            short8 af = *(const short8*)(Aarr + (size_t)arow * 128 + kb);
            const int kf = c * 32 + quad * 8;
#pragma unroll
            for (int nt = 0; nt < 8; ++nt) {
                short8 bf = *(const short8*)(Bs + (nt * 16 + lrow) * BSTRIDE + kf);
                acc[nt] = __builtin_amdgcn_mfma_f32_16x16x32_bf16(af, bf, acc[nt], 0, 0, 0);
            }
        }

        float gpart[4] = {0.f, 0.f, 0.f, 0.f};
#pragma unroll
        for (int nt = 0; nt < 8; ++nt) {
            int col = nt * 16 + lrow;
            float bc = bias[col];
            float gw = gatew ? gatew[col] : 0.f;
#pragma unroll
            for (int r = 0; r < 4; ++r) {
                int row = row0 + quad * 4 + r;
                if (row < N_NODES) {
                    float v = fmaxf(acc[nt][r] + bc, 0.f);
                    Out[(size_t)row * 128 + col] = f2b(v);
                    gpart[r] += v * gw;
                }
            }
        }
        if (gatew) {
            float gb = gateb[0];
#pragma unroll
            for (int r = 0; r < 4; ++r) {
                float g = gpart[r];
                g += __shfl_xor(g, 1);
                g += __shfl_xor(g, 2);
                g += __shfl_xor(g, 4);
                g += __shfl_xor(g, 8);
                if (lrow == 0) {
                    int row = row0 + quad * 4 + r;
                    if (row < N_NODES) gate[row] = g + gb;
                }
            }
        }
    }
}

// ---------------- fused attention-pool + MLP + log_softmax: one wave per graph ----------------
__global__ __launch_bounds__(64) void pool_mlp_kernel(const unsigned short* __restrict__ h,
                                                      const float* __restrict__ gate,
                                                      const int* __restrict__ gstart,
                                                      const float* __restrict__ l1w,
                                                      const float* __restrict__ l1b,
                                                      const float* __restrict__ l2w,
                                                      const float* __restrict__ l2b,
                                                      float* __restrict__ out) {
    int g = blockIdx.x;
    int lane = threadIdx.x;
    __shared__ float pooled_s[128];
    __shared__ float hid_s[128];

    int beg = gstart[g], end = gstart[g + 1];

    float m = -INFINITY;
    for (int i = beg + lane; i < end; i += 64) m = fmaxf(m, gate[i]);
#pragma unroll
    for (int o = 32; o; o >>= 1) m = fmaxf(m, __shfl_xor(m, o));
    float s = 0.f;
    for (int i = beg + lane; i < end; i += 64) s += expf(gate[i] - m);
#pragma unroll
    for (int o = 32; o; o >>= 1) s += __shfl_xor(s, o);
    float invs = (s > 0.f) ? 1.0f / s : 0.f;

    float ax = 0.f, ay = 0.f;
    const unsigned* hb = (const unsigned*)h;
    int i = beg;
    for (; i + 2 <= end; i += 2) {
        float w0 = expf(gate[i] - m) * invs;
        float w1 = expf(gate[i + 1] - m) * invs;
        unsigned v0 = hb[(size_t)i * 64 + lane];
        unsigned v1 = hb[(size_t)(i + 1) * 64 + lane];
        ax += w0 * lo16(v0) + w1 * lo16(v1);
        ay += w0 * hi16(v0) + w1 * hi16(v1);
    }
    for (; i < end; ++i) {
        float w = expf(gate[i] - m) * invs;
        unsigned v = hb[(size_t)i * 64 + lane];
        ax += w * lo16(v);
        ay += w * hi16(v);
    }
    pooled_s[2 * lane] = ax;
    pooled_s[2 * lane + 1] = ay;
    __syncthreads();

    float h0 = l1b[lane], h1 = l1b[lane + 64];
    for (int k = 0; k < 128; ++k) {
        float pv = pooled_s[k];
        h0 += pv * l1w[k * 128 + lane];
        h1 += pv * l1w[k * 128 + lane + 64];
    }
    hid_s[lane] = fmaxf(h0, 0.f);
    hid_s[lane + 64] = fmaxf(h1, 0.f);
    __syncthreads();

    float o10 = 0.f;
    if (lane < NC) {
        o10 = l2b[lane];
        for (int k = 0; k < 128; ++k) o10 += hid_s[k] * l2w[k * NC + lane];
    }
    float mm = -INFINITY;
#pragma unroll
    for (int j = 0; j < NC; ++j) mm = fmaxf(mm, __shfl(o10, j));
    float ss = 0.f;
#pragma unroll
    for (int j = 0; j < NC; ++j) ss += expf(__shfl(o10, j) - mm);
    float lse = mm + logf(ss);
    if (lane < NC) out[g * NC + lane] = o10 - lse;
}

extern "C" void kernel_launch(void* const* d_in, const int* in_sizes, int n_in,
                              void* d_out, int out_size, void* d_ws, size_t ws_size,
                              hipStream_t stream) {
    const float* x   = (const float*)d_in[0];
    const int* ei    = (const int*)d_in[1];
    const int* batch = (const int*)d_in[2];
    const float* w1l = (const float*)d_in[3];
    const float* b1  = (const float*)d_in[4];
    const float* w1r = (const float*)d_in[5];
    const float* w2l = (const float*)d_in[6];
    const float* b2  = (const float*)d_in[7];
    const float* w2r = (const float*)d_in[8];
    const float* w3l = (const float*)d_in[9];
    const float* b3  = (const float*)d_in[10];
    const float* w3r = (const float*)d_in[11];
    const float* gw  = (const float*)d_in[12];
    const float* gb  = (const float*)d_in[13];
    const float* l1w = (const float*)d_in[14];
    const float* l1b = (const float*)d_in[15];
    const float* l2w = (const float*)d_in[16];
    const float* l2b = (const float*)d_in[17];
    float* out = (float*)d_out;

    const int* src = ei;
    const int* dst = ei + N_EDGES;

    char* base = (char*)d_ws;
    size_t off = 0;
    auto carve = [&](size_t bytes) -> void* {
        void* r = base + off;
        off = (off + bytes + 255) & ~(size_t)255;
        return r;
    };
    int* rowptr         = (int*)carve((size_t)(N_NODES + 1) * 4);
    int* eidx           = (int*)carve((size_t)N_EDGES * 4);
    unsigned short* Bt  = (unsigned short*)carve((size_t)3 * 128 * 256 * 2);
    unsigned short* xb  = (unsigned short*)carve((size_t)N_NODES * NF * 2);
    unsigned short* mn  = (unsigned short*)carve((size_t)N_NODES * NF * 2);
    unsigned short* hA  = (unsigned short*)carve((size_t)N_NODES * NF * 2);
    unsigned short* hB  = (unsigned short*)carve((size_t)N_NODES * NF * 2);
    float* gate         = (float*)carve((size_t)N_NODES * 4);
    int* gstart         = (int*)carve(513 * 4);
    int* bcount         = (int*)carve((NBUCK + 1) * 4);
    int* bbase          = (int*)carve((NBUCK + 1) * 4);
    int* gcursor        = (int*)carve((NBUCK + 1) * 4);
    unsigned* brec      = (unsigned*)mn;  // alias: mn is dead until the first agg_kernel

    hipMemsetAsync(bcount, 0, (size_t)NBUCK * 4, stream);

    prep_kernel<<<CVT_B + BT_B + BOUNDS_B + COUNT_B, 256, 0, stream>>>(
        x, xb, w1l, w1r, w2l, w2r, w3l, w3r, Bt, batch, gstart, dst, bcount);

    bucket_scan<<<1, 512, 0, stream>>>(bcount, bbase, gcursor, rowptr);
    bucket_scatter<<<COUNT_B, 256, 0, stream>>>(src, dst, gcursor, brec);
    bucket_fill<<<NBUCK, 256, 0, stream>>>(brec, bbase, rowptr, eidx);

    const int AGG_B = (N_NODES + 3) / 4;  // 25000

    agg_kernel<<<AGG_B, 256, 0, stream>>>(xb, rowptr, eidx, mn);
    gemm_kernel<<<GEMM_GRID, 256, 0, stream>>>(mn, xb, Bt, b1, hA, nullptr, nullptr, nullptr);
    agg_kernel<<<AGG_B, 256, 0, stream>>>(hA, rowptr, eidx, mn);
    gemm_kernel<<<GEMM_GRID, 256, 0, stream>>>(mn, hA, Bt + 32768, b2, hB, nullptr, nullptr, nullptr);
    agg_kernel<<<AGG_B, 256, 0, stream>>>(hB, rowptr, eidx, mn);
    gemm_kernel<<<GEMM_GRID, 256, 0, stream>>>(mn, hB, Bt + 65536, b3, hA, gw, gb, gate);

    pool_mlp_kernel<<<NG, 64, 0, stream>>>(hA, gate, gstart, l1w, l1b, l2w, l2b, out);
}

// Round 12
// 475.195 us; speedup vs baseline: 1.4378x; 1.2237x over previous
//
#include <hip/hip_runtime.h>
#include <stdint.h>

#define N_NODES 100000
#define N_EDGES 1600000
#define NF 128
#define NG 512
#define NC 10

#define NBUCK ((N_NODES + 255) / 256)  // 391 buckets of 256 nodes
#define EPB 4096                       // edges per block in bucket passes

#define KSTRIDE 136                    // shorts per LDS B row (128 k-half + 8 pad) = 272 B
#define GEMM_B ((N_NODES + 127) / 128) // 782 blocks, 128 rows each

#define CVT_B 6250                     // cvt blocks
#define BT_B 384                       // build_bt blocks
#define BOUNDS_B 3                     // bounds blocks
#define COUNT_B ((N_EDGES + EPB - 1) / EPB)  // 391 bucket-count blocks

typedef short short8 __attribute__((ext_vector_type(8)));
typedef float f32x4 __attribute__((ext_vector_type(4)));

__device__ __forceinline__ unsigned short f2b(float f) {
    unsigned u = __float_as_uint(f);
    u += 0x7fffu + ((u >> 16) & 1u);
    return (unsigned short)(u >> 16);
}
__device__ __forceinline__ float lo16(unsigned v) { return __uint_as_float(v << 16); }
__device__ __forceinline__ float hi16(unsigned v) { return __uint_as_float(v & 0xffff0000u); }

// ---------------- prep: cvt (x->bf16) + build_bt + bounds + bucket_count, merged ----------------
__global__ __launch_bounds__(256) void prep_kernel(const float* __restrict__ x, unsigned short* __restrict__ xb,
                                                   const float* __restrict__ w1l, const float* __restrict__ w1r,
                                                   const float* __restrict__ w2l, const float* __restrict__ w2r,
                                                   const float* __restrict__ w3l, const float* __restrict__ w3r,
                                                   unsigned short* __restrict__ Bt,
                                                   const int* __restrict__ batch, int* __restrict__ gstart,
                                                   const int* __restrict__ dst, int* __restrict__ bcount) {
    const int b = blockIdx.x, t = threadIdx.x;
    if (b < CVT_B) {
        int i = b * 256 + t;
        const float4* ip = (const float4*)x;
        float4 a = ip[2 * i], c = ip[2 * i + 1];
        uint4 o;
        o.x = (unsigned)f2b(a.x) | ((unsigned)f2b(a.y) << 16);
        o.y = (unsigned)f2b(a.z) | ((unsigned)f2b(a.w) << 16);
        o.z = (unsigned)f2b(c.x) | ((unsigned)f2b(c.y) << 16);
        o.w = (unsigned)f2b(c.z) | ((unsigned)f2b(c.w) << 16);
        ((uint4*)xb)[i] = o;
    } else if (b < CVT_B + BT_B) {
        int i = (b - CVT_B) * 256 + t;
        int layer = i / (128 * 256);
        int r = i % (128 * 256);
        int n = r / 256, k = r % 256;
        const float* wl = (layer == 0) ? w1l : (layer == 1) ? w2l : w3l;
        const float* wr = (layer == 0) ? w1r : (layer == 1) ? w2r : w3r;
        float v = (k < 128) ? wl[k * 128 + n] : wr[(k - 128) * 128 + n];
        Bt[i] = f2b(v);
    } else if (b < CVT_B + BT_B + BOUNDS_B) {
        int g = (b - CVT_B - BT_B) * 256 + t;
        if (g > NG) return;
        int lo = 0, hi = N_NODES;
        while (lo < hi) {
            int mid = (lo + hi) >> 1;
            if (batch[mid] < g) lo = mid + 1; else hi = mid;
        }
        gstart[g] = lo;
    } else {
        __shared__ int h[NBUCK];
        for (int i = t; i < NBUCK; i += 256) h[i] = 0;
        __syncthreads();
        const int base = (b - CVT_B - BT_B - BOUNDS_B) * EPB;
        const int lim = min(base + EPB, N_EDGES);
        for (int i = base + t; i < lim; i += 256) atomicAdd(&h[dst[i] >> 8], 1);
        __syncthreads();
        for (int i = t; i < NBUCK; i += 256)
            if (h[i]) atomicAdd(&bcount[i], h[i]);
    }
}

// ---------------- CSR build (scan / scatter / fill) ----------------
__global__ __launch_bounds__(512) void bucket_scan(const int* __restrict__ bcount, int* __restrict__ bbase,
                                                   int* __restrict__ gcursor, int* __restrict__ rowptr) {
    __shared__ int sh[512];
    const int t = threadIdx.x;
    int v = (t < NBUCK) ? bcount[t] : 0;
    sh[t] = v;
    __syncthreads();
    for (int off = 1; off < 512; off <<= 1) {
        int u = (t >= off) ? sh[t - off] : 0;
        __syncthreads();
        sh[t] += u;
        __syncthreads();
    }
    if (t < NBUCK) {
        int e = sh[t] - v;
        bbase[t] = e;
        gcursor[t] = e;
    }
    if (t == NBUCK - 1) bbase[NBUCK] = sh[t];
    if (t == 0) rowptr[N_NODES] = N_EDGES;
}

__global__ __launch_bounds__(256) void bucket_scatter(const int* __restrict__ src, const int* __restrict__ dst,
                                                      int* __restrict__ gcursor, unsigned* __restrict__ brec) {
    __shared__ int h[NBUCK];
    for (int i = threadIdx.x; i < NBUCK; i += 256) h[i] = 0;
    __syncthreads();
    const int base = blockIdx.x * EPB;
    const int lim = min(base + EPB, N_EDGES);
    for (int i = base + threadIdx.x; i < lim; i += 256) atomicAdd(&h[dst[i] >> 8], 1);
    __syncthreads();
    for (int i = threadIdx.x; i < NBUCK; i += 256) {
        int c = h[i];
        if (c) h[i] = atomicAdd(&gcursor[i], c);
    }
    __syncthreads();
    for (int i = base + threadIdx.x; i < lim; i += 256) {
        int d = dst[i];
        int pos = atomicAdd(&h[d >> 8], 1);
        brec[pos] = ((unsigned)(d & 255) << 17) | (unsigned)src[i];
    }
}

__global__ __launch_bounds__(256) void bucket_fill(const unsigned* __restrict__ brec, const int* __restrict__ bbase,
                                                   int* __restrict__ rowptr, int* __restrict__ eidx) {
    __shared__ int nh[256];
    __shared__ int sc[256];
    const int b = blockIdx.x, t = threadIdx.x;
    const int beg = bbase[b], end = bbase[b + 1];
    nh[t] = 0;
    __syncthreads();
    for (int i = beg + t; i < end; i += 256) atomicAdd(&nh[brec[i] >> 17], 1);
    __syncthreads();
    int cnt = nh[t];
    sc[t] = cnt;
    __syncthreads();
    for (int off = 1; off < 256; off <<= 1) {
        int u = (t >= off) ? sc[t - off] : 0;
        __syncthreads();
        sc[t] += u;
        __syncthreads();
    }
    int excl = sc[t] - cnt;
    int node = b * 256 + t;
    if (node < N_NODES) rowptr[node] = beg + excl;
    nh[t] = beg + excl;
    __syncthreads();
    for (int i = beg + t; i < end; i += 256) {
        unsigned r = brec[i];
        int pos = atomicAdd(&nh[r >> 17], 1);
        eidx[pos] = (int)(r & 0x1FFFFu);
    }
}

// ---------------- mean aggregation: one wave per node; quad q owns edges beg+q, beg+q+4, ... ----------------
__global__ __launch_bounds__(256) void agg_kernel(const unsigned short* __restrict__ F,
                                                  const int* __restrict__ rowptr,
                                                  const int* __restrict__ eidx,
                                                  unsigned short* __restrict__ M) {
    int node = blockIdx.x * 4 + (threadIdx.x >> 6);
    if (node >= N_NODES) return;
    const int lane = threadIdx.x & 63;
    const int quad = lane >> 4, ql = lane & 15;
    const int beg = rowptr[node], end = rowptr[node + 1];
    const uint4* F4 = (const uint4*)F;

    float a0 = 0.f, a1 = 0.f, a2 = 0.f, a3 = 0.f, a4 = 0.f, a5 = 0.f, a6 = 0.f, a7 = 0.f;
    int t = beg + quad;
    for (; t + 12 < end; t += 16) {
        int r0 = eidx[t];
        int r1 = eidx[t + 4];
        int r2 = eidx[t + 8];
        int r3 = eidx[t + 12];
        uint4 v0 = F4[(size_t)r0 * 16 + ql];
        uint4 v1 = F4[(size_t)r1 * 16 + ql];
        uint4 v2 = F4[(size_t)r2 * 16 + ql];
        uint4 v3 = F4[(size_t)r3 * 16 + ql];
        a0 += lo16(v0.x) + lo16(v1.x) + lo16(v2.x) + lo16(v3.x);
        a1 += hi16(v0.x) + hi16(v1.x) + hi16(v2.x) + hi16(v3.x);
        a2 += lo16(v0.y) + lo16(v1.y) + lo16(v2.y) + lo16(v3.y);
        a3 += hi16(v0.y) + hi16(v1.y) + hi16(v2.y) + hi16(v3.y);
        a4 += lo16(v0.z) + lo16(v1.z) + lo16(v2.z) + lo16(v3.z);
        a5 += hi16(v0.z) + hi16(v1.z) + hi16(v2.z) + hi16(v3.z);
        a6 += lo16(v0.w) + lo16(v1.w) + lo16(v2.w) + lo16(v3.w);
        a7 += hi16(v0.w) + hi16(v1.w) + hi16(v2.w) + hi16(v3.w);
    }
    for (; t < end; t += 4) {
        uint4 v0 = F4[(size_t)eidx[t] * 16 + ql];
        a0 += lo16(v0.x); a1 += hi16(v0.x);
        a2 += lo16(v0.y); a3 += hi16(v0.y);
        a4 += lo16(v0.z); a5 += hi16(v0.z);
        a6 += lo16(v0.w); a7 += hi16(v0.w);
    }
    a0 += __shfl_xor(a0, 16); a0 += __shfl_xor(a0, 32);
    a1 += __shfl_xor(a1, 16); a1 += __shfl_xor(a1, 32);
    a2 += __shfl_xor(a2, 16); a2 += __shfl_xor(a2, 32);
    a3 += __shfl_xor(a3, 16); a3 += __shfl_xor(a3, 32);
    a4 += __shfl_xor(a4, 16); a4 += __shfl_xor(a4, 32);
    a5 += __shfl_xor(a5, 16); a5 += __shfl_xor(a5, 32);
    a6 += __shfl_xor(a6, 16); a6 += __shfl_xor(a6, 32);
    a7 += __shfl_xor(a7, 16); a7 += __shfl_xor(a7, 32);

    if (quad == 0) {
        float inv = 1.0f / (float)max(end - beg, 1);
        uint4 o;
        o.x = (unsigned)f2b(a0 * inv) | ((unsigned)f2b(a1 * inv) << 16);
        o.y = (unsigned)f2b(a2 * inv) | ((unsigned)f2b(a3 * inv) << 16);
        o.z = (unsigned)f2b(a4 * inv) | ((unsigned)f2b(a5 * inv) << 16);
        o.w = (unsigned)f2b(a6 * inv) | ((unsigned)f2b(a7 * inv) << 16);
        ((uint4*)M)[(size_t)node * 16 + ql] = o;
    }
}

// ---------------- GEMM: H = relu([mean|feat] @ Bt^T + b), optional fused gate ----------------
// K-split LDS: stage 128 B-rows x 128 k-half (34.8 KB) per pass; 128 rows/block,
// each wave = 2 row-tiles x 8 col-tiles 16x16x32 MFMA. Packed 4-byte epilogue stores.
__global__ __launch_bounds__(256, 4) void gemm_kernel(const unsigned short* __restrict__ Am,
                                                      const unsigned short* __restrict__ Ax,
                                                      const unsigned short* __restrict__ Bt,
                                                      const float* __restrict__ bias,
                                                      unsigned short* __restrict__ Out,
                                                      const float* __restrict__ gatew,
                                                      const float* __restrict__ gateb,
                                                      float* __restrict__ gate) {
    const int t = threadIdx.x;
    const int wave = t >> 6, lane = t & 63;
    const int lrow = lane & 15, quad = lane >> 4;
    const int row0 = blockIdx.x * 128 + wave * 32;

    __shared__ __attribute__((aligned(16))) unsigned short Bs[128 * KSTRIDE];  // 34.8 KB

    f32x4 acc[2][8];
#pragma unroll
    for (int i = 0; i < 2; ++i)
#pragma unroll
        for (int j = 0; j < 8; ++j) acc[i][j] = (f32x4){0.f, 0.f, 0.f, 0.f};

    int arow0 = row0 + lrow;          if (arow0 > N_NODES - 1) arow0 = N_NODES - 1;
    int arow1 = row0 + 16 + lrow;     if (arow1 > N_NODES - 1) arow1 = N_NODES - 1;

    for (int p = 0; p < 2; ++p) {
        if (p) __syncthreads();  // all waves done reading pass-0 Bs
        // stage k-half p: 128 rows x 16 uint4 = 2048 units, 8 per thread
#pragma unroll
        for (int i = 0; i < 8; ++i) {
            int u = t + i * 256;
            int r = u >> 4, seg = u & 15;
            *(uint4*)(Bs + r * KSTRIDE + seg * 8) =
                *(const uint4*)(Bt + (size_t)r * 256 + p * 128 + seg * 8);
        }
        __syncthreads();

        const unsigned short* Aarr = p ? Ax : Am;
#pragma unroll
        for (int c = 0; c < 4; ++c) {
            const int kb = c * 32 + quad * 8;
            short8 af0 = *(const short8*)(Aarr + (size_t)arow0 * 128 + kb);
            short8 af1 = *(const short8*)(Aarr + (size_t)arow1 * 128 + kb);
#pragma unroll
            for (int nt = 0; nt < 8; ++nt) {
                short8 bf = *(const short8*)(Bs + (nt * 16 + lrow) * KSTRIDE + kb);
                acc[0][nt] = __builtin_amdgcn_mfma_f32_16x16x32_bf16(af0, bf, acc[0][nt], 0, 0, 0);
                acc[1][nt] = __builtin_amdgcn_mfma_f32_16x16x32_bf16(af1, bf, acc[1][nt], 0, 0, 0);
            }
        }
    }

    float gpart[2][4];
#pragma unroll
    for (int i = 0; i < 2; ++i)
#pragma unroll
        for (int r = 0; r < 4; ++r) gpart[i][r] = 0.f;

#pragma unroll
    for (int nt = 0; nt < 8; ++nt) {
        int col = nt * 16 + lrow;
        float bc = bias[col];
        float gw = gatew ? gatew[col] : 0.f;
#pragma unroll
        for (int i = 0; i < 2; ++i) {
            int rbase = row0 + i * 16 + quad * 4;
#pragma unroll
            for (int r = 0; r < 4; ++r) {
                int row = rbase + r;
                float v = fmaxf(acc[i][nt][r] + bc, 0.f);
                if (row < N_NODES) gpart[i][r] += v * gw;
                // pack col-pair: even lrow stores 4 bytes covering (col, col+1)
                unsigned sv = (unsigned)f2b(v);
                unsigned nb = (unsigned)__shfl_xor((int)sv, 1);
                if (((lrow & 1) == 0) && row < N_NODES)
                    *(unsigned*)(Out + (size_t)row * 128 + col) = sv | (nb << 16);
            }
        }
    }
    if (gatew) {
        float gb = gateb[0];
#pragma unroll
        for (int i = 0; i < 2; ++i) {
#pragma unroll
            for (int r = 0; r < 4; ++r) {
                float g = gpart[i][r];
                g += __shfl_xor(g, 1);
                g += __shfl_xor(g, 2);
                g += __shfl_xor(g, 4);
                g += __shfl_xor(g, 8);
                if (lrow == 0) {
                    int row = row0 + i * 16 + quad * 4 + r;
                    if (row < N_NODES) gate[row] = g + gb;
                }
            }
        }
    }
}

// ---------------- fused attention-pool + MLP + log_softmax: one wave per graph ----------------
__global__ __launch_bounds__(64) void pool_mlp_kernel(const unsigned short* __restrict__ h,
                                                      const float* __restrict__ gate,
                                                      const int* __restrict__ gstart,
                                                      const float* __restrict__ l1w,
                                                      const float* __restrict__ l1b,
                                                      const float* __restrict__ l2w,
                                                      const float* __restrict__ l2b,
                                                      float* __restrict__ out) {
    int g = blockIdx.x;
    int lane = threadIdx.x;
    __shared__ float pooled_s[128];
    __shared__ float hid_s[128];

    int beg = gstart[g], end = gstart[g + 1];

    float m = -INFINITY;
    for (int i = beg + lane; i < end; i += 64) m = fmaxf(m, gate[i]);
#pragma unroll
    for (int o = 32; o; o >>= 1) m = fmaxf(m, __shfl_xor(m, o));
    float s = 0.f;
    for (int i = beg + lane; i < end; i += 64) s += expf(gate[i] - m);
#pragma unroll
    for (int o = 32; o; o >>= 1) s += __shfl_xor(s, o);
    float invs = (s > 0.f) ? 1.0f / s : 0.f;

    float ax = 0.f, ay = 0.f;
    const unsigned* hb = (const unsigned*)h;
    int i = beg;
    for (; i + 2 <= end; i += 2) {
        float w0 = expf(gate[i] - m) * invs;
        float w1 = expf(gate[i + 1] - m) * invs;
        unsigned v0 = hb[(size_t)i * 64 + lane];
        unsigned v1 = hb[(size_t)(i + 1) * 64 + lane];
        ax += w0 * lo16(v0) + w1 * lo16(v1);
        ay += w0 * hi16(v0) + w1 * hi16(v1);
    }
    for (; i < end; ++i) {
        float w = expf(gate[i] - m) * invs;
        unsigned v = hb[(size_t)i * 64 + lane];
        ax += w * lo16(v);
        ay += w * hi16(v);
    }
    pooled_s[2 * lane] = ax;
    pooled_s[2 * lane + 1] = ay;
    __syncthreads();

    float h0 = l1b[lane], h1 = l1b[lane + 64];
    for (int k = 0; k < 128; ++k) {
        float pv = pooled_s[k];
        h0 += pv * l1w[k * 128 + lane];
        h1 += pv * l1w[k * 128 + lane + 64];
    }
    hid_s[lane] = fmaxf(h0, 0.f);
    hid_s[lane + 64] = fmaxf(h1, 0.f);
    __syncthreads();

    float o10 = 0.f;
    if (lane < NC) {
        o10 = l2b[lane];
        for (int k = 0; k < 128; ++k) o10 += hid_s[k] * l2w[k * NC + lane];
    }
    float mm = -INFINITY;
#pragma unroll
    for (int j = 0; j < NC; ++j) mm = fmaxf(mm, __shfl(o10, j));
    float ss = 0.f;
#pragma unroll
    for (int j = 0; j < NC; ++j) ss += expf(__shfl(o10, j) - mm);
    float lse = mm + logf(ss);
    if (lane < NC) out[g * NC + lane] = o10 - lse;
}

extern "C" void kernel_launch(void* const* d_in, const int* in_sizes, int n_in,
                              void* d_out, int out_size, void* d_ws, size_t ws_size,
                              hipStream_t stream) {
    const float* x   = (const float*)d_in[0];
    const int* ei    = (const int*)d_in[1];
    const int* batch = (const int*)d_in[2];
    const float* w1l = (const float*)d_in[3];
    const float* b1  = (const float*)d_in[4];
    const float* w1r = (const float*)d_in[5];
    const float* w2l = (const float*)d_in[6];
    const float* b2  = (const float*)d_in[7];
    const float* w2r = (const float*)d_in[8];
    const float* w3l = (const float*)d_in[9];
    const float* b3  = (const float*)d_in[10];
    const float* w3r = (const float*)d_in[11];
    const float* gw  = (const float*)d_in[12];
    const float* gb  = (const float*)d_in[13];
    const float* l1w = (const float*)d_in[14];
    const float* l1b = (const float*)d_in[15];
    const float* l2w = (const float*)d_in[16];
    const float* l2b = (const float*)d_in[17];
    float* out = (float*)d_out;

    const int* src = ei;
    const int* dst = ei + N_EDGES;

    char* base = (char*)d_ws;
    size_t off = 0;
    auto carve = [&](size_t bytes) -> void* {
        void* r = base + off;
        off = (off + bytes + 255) & ~(size_t)255;
        return r;
    };
    int* rowptr         = (int*)carve((size_t)(N_NODES + 1) * 4);
    int* eidx           = (int*)carve((size_t)N_EDGES * 4);
    unsigned short* Bt  = (unsigned short*)carve((size_t)3 * 128 * 256 * 2);
    unsigned short* xb  = (unsigned short*)carve((size_t)N_NODES * NF * 2);
    unsigned short* mn  = (unsigned short*)carve((size_t)N_NODES * NF * 2);
    unsigned short* hA  = (unsigned short*)carve((size_t)N_NODES * NF * 2);
    unsigned short* hB  = (unsigned short*)carve((size_t)N_NODES * NF * 2);
    float* gate         = (float*)carve((size_t)N_NODES * 4);
    int* gstart         = (int*)carve(513 * 4);
    int* bcount         = (int*)carve((NBUCK + 1) * 4);
    int* bbase          = (int*)carve((NBUCK + 1) * 4);
    int* gcursor        = (int*)carve((NBUCK + 1) * 4);
    unsigned* brec      = (unsigned*)mn;  // alias: mn is dead until the first agg_kernel

    hipMemsetAsync(bcount, 0, (size_t)NBUCK * 4, stream);

    prep_kernel<<<CVT_B + BT_B + BOUNDS_B + COUNT_B, 256, 0, stream>>>(
        x, xb, w1l, w1r, w2l, w2r, w3l, w3r, Bt, batch, gstart, dst, bcount);

    bucket_scan<<<1, 512, 0, stream>>>(bcount, bbase, gcursor, rowptr);
    bucket_scatter<<<COUNT_B, 256, 0, stream>>>(src, dst, gcursor, brec);
    bucket_fill<<<NBUCK, 256, 0, stream>>>(brec, bbase, rowptr, eidx);

    const int AGG_B = (N_NODES + 3) / 4;  // 25000

    agg_kernel<<<AGG_B, 256, 0, stream>>>(xb, rowptr, eidx, mn);
    gemm_kernel<<<GEMM_B, 256, 0, stream>>>(mn, xb, Bt, b1, hA, nullptr, nullptr, nullptr);
    agg_kernel<<<AGG_B, 256, 0, stream>>>(hA, rowptr, eidx, mn);
    gemm_kernel<<<GEMM_B, 256, 0, stream>>>(mn, hA, Bt + 32768, b2, hB, nullptr, nullptr, nullptr);
    agg_kernel<<<AGG_B, 256, 0, stream>>>(hB, rowptr, eidx, mn);
    gemm_kernel<<<GEMM_B, 256, 0, stream>>>(mn, hB, Bt + 65536, b3, hA, gw, gb, gate);

    pool_mlp_kernel<<<NG, 64, 0, stream>>>(hA, gate, gstart, l1w, l1b, l2w, l2b, out);
}